// Round 12
// baseline (210.574 us; speedup 1.0000x reference)
//
#include <hip/hip_runtime.h>
#include <stddef.h>

#define B_ 2
#define L_ 384
#define D_ 1024
#define K_ 128
#define H_ 32

#define MINV (-3.402823466e38f)
// Exported -inf sentinel: must stay FINITE after bf16 rounding (bf16 max ~3.39e38).
#define NEG_BIG (-1.0e38f)
#define SCALING_ 0.08838834764831845f
#define INV_SQRT_2PI 0.3989422804014327f

typedef __attribute__((ext_vector_type(8))) short bf16x8;
typedef __attribute__((ext_vector_type(4))) float f32x4;

__device__ __forceinline__ float finitize(float x) {
    return fminf(fmaxf(x, -1.0e38f), 1.0e38f);
}
__device__ __forceinline__ unsigned short f2bf(float x) {
    unsigned int u = __float_as_uint(x);
    u += 0x7FFFu + ((u >> 16) & 1u);
    return (unsigned short)(u >> 16);
}
__device__ __forceinline__ unsigned short f2bf_rtz(float x) {
    return (unsigned short)(__float_as_uint(x) >> 16);
}
// 8 consecutive f32 -> bf16x8 fragment (RNE)
__device__ __forceinline__ bf16x8 cvt8(const float* __restrict__ p) {
    const float4 a = *(const float4*)p;
    const float4 b = *(const float4*)(p + 4);
    union { unsigned short u[8]; bf16x8 v; } r;
    r.u[0] = f2bf(a.x); r.u[1] = f2bf(a.y); r.u[2] = f2bf(a.z); r.u[3] = f2bf(a.w);
    r.u[4] = f2bf(b.x); r.u[5] = f2bf(b.y); r.u[6] = f2bf(b.z); r.u[7] = f2bf(b.w);
    return r.v;
}
// tanh-form gelu: max abs err ~3e-4, 1 exp + 1 rcp
__device__ __forceinline__ float gelu_tanh(float x) {
    const float x2 = x * x;
    const float z = x * fmaf(0.0356774081f, x2, 0.7978845608f);
    const float e = __expf(2.0f * z);
    const float t = fmaf(-2.0f, __builtin_amdgcn_rcpf(e + 1.0f), 1.0f);
    const float hx = 0.5f * x;
    return fmaf(hx, t, hx);
}

// ---------------------------------------------------------------------------
// time-MLP GEMM body (used for ts2 phase): A bf16 (M,Kd), B f32 (N,Kd)
// converted in staging. BM=32, BN=64, BK=64, 4 waves, register prefetch.
// acc returned via accOut when Cv==nullptr.
// smem: sA[32][72] us @0 (4608 B), sB[64][72] us @4608 (9216 B) = 13824 B
// ---------------------------------------------------------------------------
__device__ __forceinline__ void gemm_ts_body(
    char* smem, int m0, int n0,
    const unsigned short* __restrict__ A, const float* __restrict__ Bw,
    const float* __restrict__ bias, void* __restrict__ Cv,
    int N, int Kd, int act, f32x4* accOut)
{
    unsigned short (*sA)[72] = (unsigned short(*)[72])smem;
    unsigned short (*sB)[72] = (unsigned short(*)[72])(smem + 4608);
    const int tid  = threadIdx.x;
    const int lane = tid & 63;
    const int wave = tid >> 6;
    const int l15  = lane & 15;
    const int quad = lane >> 4;
    const int mt   = wave & 1;
    const int np   = wave >> 1;

    const int ar = tid >> 3, ac = (tid & 7) * 8;
    const int bc4 = (tid & 15) * 4;

    f32x4 acc[2];
#pragma unroll
    for (int t = 0; t < 2; ++t) acc[t] = (f32x4){0.f, 0.f, 0.f, 0.f};

    uint4 ra = *(const uint4*)&A[(size_t)(m0 + ar) * Kd + ac];
    float4 rbv[4];
#pragma unroll
    for (int c = 0; c < 4; ++c)
        rbv[c] = *(const float4*)&Bw[(size_t)(n0 + ((tid + c * 256) >> 4)) * Kd + bc4];

    for (int k0 = 0; k0 < Kd; k0 += 64) {
        *(uint4*)&sA[ar][ac] = ra;
#pragma unroll
        for (int c = 0; c < 4; ++c) {
            ushort4 p;
            p.x = f2bf(rbv[c].x); p.y = f2bf(rbv[c].y);
            p.z = f2bf(rbv[c].z); p.w = f2bf(rbv[c].w);
            *(ushort4*)&sB[(tid + c * 256) >> 4][bc4] = p;
        }
        __syncthreads();
        if (k0 + 64 < Kd) {
            ra = *(const uint4*)&A[(size_t)(m0 + ar) * Kd + k0 + 64 + ac];
#pragma unroll
            for (int c = 0; c < 4; ++c)
                rbv[c] = *(const float4*)&Bw[(size_t)(n0 + ((tid + c * 256) >> 4)) * Kd + k0 + 64 + bc4];
        }
#pragma unroll
        for (int kk = 0; kk < 64; kk += 32) {
            const bf16x8 av = *(const bf16x8*)&sA[mt * 16 + l15][kk + quad * 8];
#pragma unroll
            for (int t = 0; t < 2; ++t) {
                const bf16x8 bv = *(const bf16x8*)&sB[(np * 2 + t) * 16 + l15][kk + quad * 8];
                acc[t] = __builtin_amdgcn_mfma_f32_16x16x32_bf16(av, bv, acc[t], 0, 0, 0);
            }
        }
        __syncthreads();
    }
    if (accOut) {
        accOut[0] = acc[0];
        accOut[1] = acc[1];
        return;
    }
#pragma unroll
    for (int t = 0; t < 2; ++t) {
        const int nc = n0 + (np * 2 + t) * 16 + l15;
        const float bv = bias[nc];
#pragma unroll
        for (int r = 0; r < 4; ++r) {
            const int mr = m0 + mt * 16 + quad * 4 + r;
            float v = acc[t][r] + bv;
            if (act) {
                v = v / (1.0f + __expf(-v));
                ((unsigned short*)Cv)[(size_t)mr * N + nc] = f2bf(v);
            } else {
                ((float*)Cv)[(size_t)mr * N + nc] = v;
            }
        }
    }
}

// ---------------------------------------------------------------------------
// ts1 body: h1 = silu(sin_emb @ Wt1^T + bt1) -> bf16. A (sinusoidal features)
// computed INLINE per K-tile (no sin_bf buffer, no prep dependency);
// B = Wt1 f32 converted in staging. BM=32, BN=64, BK=64.
// ---------------------------------------------------------------------------
__device__ __forceinline__ void ts1_body(
    char* smem, int m0, int n0,
    const float* __restrict__ time_step,
    const unsigned char* __restrict__ clean,
    const float* __restrict__ Wt1,
    const float* __restrict__ bt1,
    unsigned short* __restrict__ h1_bf)
{
    unsigned short (*sA)[72] = (unsigned short(*)[72])smem;
    unsigned short (*sB)[72] = (unsigned short(*)[72])(smem + 4608);
    const int tid  = threadIdx.x;
    const int lane = tid & 63;
    const int wave = tid >> 6;
    const int l15  = lane & 15;
    const int quad = lane >> 4;
    const int mt   = wave & 1;
    const int np   = wave >> 1;

    const int ar = tid >> 3, ac = (tid & 7) * 8;
    const int bc4 = (tid & 15) * 4;
    const int mra = m0 + ar;
    const float tval = (clean[mra] ? 0.0f : time_step[mra]) * 1000.0f;
    const float Lc = -9.210340371976184f * (1.0f / 512.0f);

    f32x4 acc[2];
#pragma unroll
    for (int t = 0; t < 2; ++t) acc[t] = (f32x4){0.f, 0.f, 0.f, 0.f};

    float4 rbv[4];
#pragma unroll
    for (int c = 0; c < 4; ++c)
        rbv[c] = *(const float4*)&Wt1[(size_t)(n0 + ((tid + c * 256) >> 4)) * D_ + bc4];

    for (int k0 = 0; k0 < D_; k0 += 64) {
        // ---- inline sinusoidal A chunk: cols k0+ac .. k0+ac+7 (never crosses 512)
        {
            union { unsigned short u[8]; uint4 q; } pk;
            const int cbase = k0 + ac;
            const bool issin = (cbase < 512);
            const int cb0 = issin ? cbase : (cbase - 512);
#pragma unroll
            for (int cc = 0; cc < 8; ++cc) {
                const float f = __expf(Lc * (float)(cb0 + cc));
                const float ang = tval * f;
                pk.u[cc] = f2bf(issin ? __sinf(ang) : __cosf(ang));
            }
            *(uint4*)&sA[ar][ac] = pk.q;
        }
#pragma unroll
        for (int c = 0; c < 4; ++c) {
            ushort4 p;
            p.x = f2bf(rbv[c].x); p.y = f2bf(rbv[c].y);
            p.z = f2bf(rbv[c].z); p.w = f2bf(rbv[c].w);
            *(ushort4*)&sB[(tid + c * 256) >> 4][bc4] = p;
        }
        __syncthreads();
        if (k0 + 64 < D_) {
#pragma unroll
            for (int c = 0; c < 4; ++c)
                rbv[c] = *(const float4*)&Wt1[(size_t)(n0 + ((tid + c * 256) >> 4)) * D_ + k0 + 64 + bc4];
        }
#pragma unroll
        for (int kk = 0; kk < 64; kk += 32) {
            const bf16x8 av = *(const bf16x8*)&sA[mt * 16 + l15][kk + quad * 8];
#pragma unroll
            for (int t = 0; t < 2; ++t) {
                const bf16x8 bv = *(const bf16x8*)&sB[(np * 2 + t) * 16 + l15][kk + quad * 8];
                acc[t] = __builtin_amdgcn_mfma_f32_16x16x32_bf16(av, bv, acc[t], 0, 0, 0);
            }
        }
        __syncthreads();
    }
#pragma unroll
    for (int t = 0; t < 2; ++t) {
        const int nc = n0 + (np * 2 + t) * 16 + l15;
        const float bv = bt1[nc];
#pragma unroll
        for (int r = 0; r < 4; ++r) {
            const int mr = m0 + mt * 16 + quad * 4 + r;
            float v = acc[t][r] + bv;
            v = v / (1.0f + __expf(-v));
            h1_bf[(size_t)mr * D_ + nc] = f2bf(v);
        }
    }
}

// ---------------------------------------------------------------------------
// Edge body (R8 structure, known-good). W1/W2 fragments converted inline
// from f32 (no prep dependency). Writes padout for its row.
// smem pool (34816 B): sEF@0 [2][32][136]us, sACT@17408 [32][136]us,
// sGab@26112 [32][33]f, sD@30336 [384]f, sRed@31872 [256]f,
// sYall@32896 [384]f, sPadCol@34432 [384]uc
// ---------------------------------------------------------------------------
__device__ __forceinline__ void edge_body(
    char* smem, int row,
    const int* __restrict__ token_id,
    const unsigned char* __restrict__ is_periodic,
    const float* __restrict__ pos,
    const unsigned char* __restrict__ adj,
    const int* __restrict__ nte,
    const float* __restrict__ gbf_means,
    const float* __restrict__ gbf_stds,
    const float* __restrict__ gbf_mul,
    const float* __restrict__ gbf_bias,
    const float* __restrict__ b1,
    const float* __restrict__ b2,
    const float* __restrict__ Wpos,
    const float* __restrict__ W1,      // (K,K) f32 row-major
    const float* __restrict__ W2,      // (H,K) f32 row-major
    unsigned short* __restrict__ pfe_bf,
    unsigned short* __restrict__ ef_bf,
    float* __restrict__ out_pab,
    float* __restrict__ padout)
{
    const int b = row / L_;
    const int i = row - b * L_;
    const int tid = threadIdx.x;

    const int tok_i = token_id[row];
    if (tid == 0) padout[row] = (tok_i == 0) ? 1.0f : 0.0f;
    if (tok_i == 0) {
        for (int idx = tid; idx < H_ * L_; idx += 256) {
            const int h = idx / L_;
            const int j = idx - h * L_;
            out_pab[((size_t)(b * H_ + h) * L_ + i) * L_ + j] = 0.0f;
        }
        if (tid < K_) {
            pfe_bf[(size_t)row * K_ + tid] = 0;
            ef_bf[(size_t)row * K_ + tid]  = 0;
        }
        return;
    }

    typedef unsigned short efbuf_t[32][136];
    efbuf_t* sEF = (efbuf_t*)smem;
    unsigned short (*sACT)[136] = (unsigned short(*)[136])(smem + 17408);
    float (*sGab)[33] = (float(*)[33])(smem + 26112);
    float* sD      = (float*)(smem + 30336);
    float* sRed    = (float*)(smem + 31872);
    float* sYall   = (float*)(smem + 32896);
    unsigned char* sPadCol = (unsigned char*)(smem + 34432);

    for (int j = tid; j < L_; j += 256)
        sPadCol[j] = (token_id[b * L_ + j] == 0) ? 1 : 0;

    const float px = pos[(size_t)row * 3 + 0];
    const float py = pos[(size_t)row * 3 + 1];
    const float pz = pos[(size_t)row * 3 + 2];
    for (int jg2 = tid; jg2 < L_; jg2 += 256) {
        const float dx = px - pos[(size_t)(b * L_ + jg2) * 3 + 0];
        const float dy = py - pos[(size_t)(b * L_ + jg2) * 3 + 1];
        const float dz = pz - pos[(size_t)(b * L_ + jg2) * 3 + 2];
        const float dist = sqrtf(fmaxf(dx * dx + dy * dy + dz * dz, 1e-12f));
        const size_t eoff = ((size_t)(b * L_ + i) * L_ + jg2) * 2;
        const int e0 = nte[eoff], e1 = nte[eoff + 1];
        sYall[jg2] = (gbf_mul[e0] + gbf_mul[e1]) * dist + (gbf_bias[e0] + gbf_bias[e1]);
    }

    const int lane = tid & 63;
    const int wave = tid >> 6;
    const int l15  = lane & 15;
    const int quad = lane >> 4;
    const int mt   = wave & 1;
    const int ntb  = (wave >> 1) * 4;
    float rb1[4];
#pragma unroll
    for (int nt = 0; nt < 4; ++nt) rb1[nt] = b1[(ntb + nt) * 16 + l15];
    const int hc = (wave >> 1) * 16 + l15;
    const float rb2 = b2[hc];
    // Hoisted B-fragments converted inline from f32 (L2-served, once/block)
    bf16x8 w1f[4][4];
#pragma unroll
    for (int ks = 0; ks < 4; ++ks)
#pragma unroll
        for (int nt = 0; nt < 4; ++nt)
            w1f[ks][nt] = cvt8(&W1[(size_t)((ntb + nt) * 16 + l15) * K_ + ks * 32 + quad * 8]);
    bf16x8 bv2[4];
#pragma unroll
    for (int ks = 0; ks < 4; ++ks)
        bv2[ks] = cvt8(&W2[(size_t)hc * K_ + ks * 32 + quad * 8]);

    const int kg4 = (tid & 31) * 4;
    const int jg  = tid >> 5;
    const int jb  = jg * 4;
    float meanv[4], istdv[4], cKv[4];
#pragma unroll
    for (int c = 0; c < 4; ++c) {
        meanv[c] = gbf_means[kg4 + c];
        const float s = fabsf(gbf_stds[kg4 + c]) + 1e-5f;
        istdv[c] = 1.0f / s;
        cKv[c]   = INV_SQRT_2PI * istdv[c];
    }
    float efs[4] = {0.f, 0.f, 0.f, 0.f};

    __syncthreads();

#pragma unroll
    for (int jj = 0; jj < 4; ++jj) {
        const int j = jb + jj;
        const float y = sYall[j];
        const bool ok = !sPadCol[j];
        ushort4 p;
#pragma unroll
        for (int c = 0; c < 4; ++c) {
            const float a = (y - meanv[c]) * istdv[c];
            const float ef = __expf(-0.5f * a * a) * cKv[c];
            ((unsigned short*)&p)[c] = f2bf_rtz(ef);
            if (ok) efs[c] += ef;
        }
        *(ushort4*)&sEF[0][j][kg4] = p;
    }
    __syncthreads();

    for (int tile = 0; tile < L_ / 32; ++tile) {
        const int jt0 = tile * 32;
        const int cur = tile & 1, nxt = cur ^ 1;

        f32x4 acc1[4];
#pragma unroll
        for (int nt = 0; nt < 4; ++nt) acc1[nt] = (f32x4){0.f, 0.f, 0.f, 0.f};
#pragma unroll
        for (int ks = 0; ks < 4; ++ks) {
            const bf16x8 av = *(const bf16x8*)&sEF[cur][mt * 16 + l15][ks * 32 + quad * 8];
#pragma unroll
            for (int nt = 0; nt < 4; ++nt)
                acc1[nt] = __builtin_amdgcn_mfma_f32_16x16x32_bf16(av, w1f[ks][nt], acc1[nt], 0, 0, 0);
        }

        if (tile + 1 < L_ / 32) {
            const int jn0 = jt0 + 32;
#pragma unroll
            for (int jj = 0; jj < 4; ++jj) {
                const int j = jb + jj;
                const float y = sYall[jn0 + j];
                const bool ok = !sPadCol[jn0 + j];
                ushort4 p;
#pragma unroll
                for (int c = 0; c < 4; ++c) {
                    const float a = (y - meanv[c]) * istdv[c];
                    const float ef = __expf(-0.5f * a * a) * cKv[c];
                    ((unsigned short*)&p)[c] = f2bf_rtz(ef);
                    if (ok) efs[c] += ef;
                }
                *(ushort4*)&sEF[nxt][j][kg4] = p;
            }
        }

#pragma unroll
        for (int nt = 0; nt < 4; ++nt) {
            const int kkc = (ntb + nt) * 16 + l15;
#pragma unroll
            for (int r = 0; r < 4; ++r) {
                const float v = gelu_tanh(acc1[nt][r] + rb1[nt]);
                sACT[mt * 16 + quad * 4 + r][kkc] = f2bf_rtz(v);
            }
        }
        __syncthreads();   // A

        f32x4 acc2 = (f32x4){0.f, 0.f, 0.f, 0.f};
#pragma unroll
        for (int ks = 0; ks < 4; ++ks) {
            const bf16x8 av = *(const bf16x8*)&sACT[mt * 16 + l15][ks * 32 + quad * 8];
            acc2 = __builtin_amdgcn_mfma_f32_16x16x32_bf16(av, bv2[ks], acc2, 0, 0, 0);
        }
        const int jl0 = mt * 16 + quad * 4;
#pragma unroll
        for (int r = 0; r < 4; ++r) sGab[jl0 + r][hc] = acc2[r] + rb2;
        __syncthreads();   // B

        {
            const int h = tid >> 3, f = tid & 7;
            const int jb2 = f * 4;
            float4 st;
#pragma unroll
            for (int r = 0; r < 4; ++r) {
                float v = finitize(sGab[jb2 + r][h]);
                if (sPadCol[jt0 + jb2 + r]) v = NEG_BIG;
                ((float*)&st)[r] = v;
            }
            *(float4*)&out_pab[((size_t)(b * H_ + h) * L_ + i) * L_ + jt0 + jb2] = st;
        }
        if (tid < 32) {
            float s = 0.0f;
#pragma unroll
            for (int h = 0; h < 32; ++h) s += sGab[tid][h];
            sD[jt0 + tid] = s;
        }
    }

    {
        float* efScr = (float*)sACT;
#pragma unroll
        for (int c = 0; c < 4; ++c) efScr[jg * 128 + kg4 + c] = efs[c];
    }
    __syncthreads();
    if (tid < 128) {
        const float* efScr = (const float*)sACT;
        float s = 0.0f;
#pragma unroll
        for (int g = 0; g < 8; ++g) s += efScr[g * 128 + tid];
        ef_bf[(size_t)row * K_ + tid] = f2bf(s);
    }
    __syncthreads();

    const bool molecule = (tok_i <= 129) && (is_periodic[b] == 0);
    float lmax = -INFINITY;
    for (int j = tid; j < L_; j += 256) {
        const bool colpad = sPadCol[j] != 0;
        const bool adj_eff = (adj[((size_t)(b * L_ + i)) * L_ + j] != 0) || (!molecule);
        const float dv = (colpad || !adj_eff) ? MINV : sD[j];
        const float s = dv * SCALING_;
        sD[j] = s;
        lmax = fmaxf(lmax, s);
    }
#pragma unroll
    for (int off = 32; off > 0; off >>= 1) lmax = fmaxf(lmax, __shfl_xor(lmax, off));
    if (lane == 0) sRed[wave] = lmax;
    __syncthreads();
    const float smax = fmaxf(fmaxf(sRed[0], sRed[1]), fmaxf(sRed[2], sRed[3]));
    float lsum = 0.0f;
    for (int j = tid; j < L_; j += 256) {
        const float e = __expf(sD[j] - smax);
        sD[j] = e;
        lsum += e;
    }
#pragma unroll
    for (int off = 32; off > 0; off >>= 1) lsum += __shfl_xor(lsum, off);
    if (lane == 0) sRed[4 + wave] = lsum;
    __syncthreads();
    const float inv = 1.0f / (sRed[4] + sRed[5] + sRed[6] + sRed[7]);

    float a0 = 0.f, a1 = 0.f, a2 = 0.f;
    for (int j = tid; j < L_; j += 256) {
        if (!sPadCol[j]) {
            const float e = sD[j];
            a0 += e * pos[(size_t)(b * L_ + j) * 3 + 0];
            a1 += e * pos[(size_t)(b * L_ + j) * 3 + 1];
            a2 += e * pos[(size_t)(b * L_ + j) * 3 + 2];
        }
    }
#pragma unroll
    for (int off = 32; off > 0; off >>= 1) {
        a0 += __shfl_xor(a0, off);
        a1 += __shfl_xor(a1, off);
        a2 += __shfl_xor(a2, off);
    }
    if (lane == 0) { sRed[8 + wave] = a0; sRed[12 + wave] = a1; sRed[16 + wave] = a2; }
    __syncthreads();
    if (tid < 128) {
        const float m0 = sRed[8] + sRed[9] + sRed[10] + sRed[11];
        const float m1 = sRed[12] + sRed[13] + sRed[14] + sRed[15];
        const float m2 = sRed[16] + sRed[17] + sRed[18] + sRed[19];
        const float w0 = Wpos[tid * 3 + 0], w1 = Wpos[tid * 3 + 1], w2 = Wpos[tid * 3 + 2];
        pfe_bf[(size_t)row * K_ + tid] = f2bf((m0 * w0 + m1 * w1 + m2 * w2) * inv);
    }
}

// ---------------------------------------------------------------------------
// Fat kernel: blocks [0,768) = edge rows; [768,1152) = time-MLP layer 1
// (inline sinusoidal A). No prep kernel needed.
// ---------------------------------------------------------------------------
__global__ __launch_bounds__(256, 3) void edge_ts1(
    const int* __restrict__ token_id,
    const unsigned char* __restrict__ is_periodic,
    const float* __restrict__ pos,
    const unsigned char* __restrict__ adj,
    const int* __restrict__ nte,
    const float* __restrict__ gbf_means,
    const float* __restrict__ gbf_stds,
    const float* __restrict__ gbf_mul,
    const float* __restrict__ gbf_bias,
    const float* __restrict__ b1,
    const float* __restrict__ b2,
    const float* __restrict__ Wpos,
    const float* __restrict__ W1,
    const float* __restrict__ W2,
    unsigned short* __restrict__ pfe_bf,
    unsigned short* __restrict__ ef_bf,
    float* __restrict__ out_pab,
    float* __restrict__ padout,
    const float* __restrict__ time_step,
    const unsigned char* __restrict__ clean,
    const float* __restrict__ Wt1,
    const float* __restrict__ bt1,
    unsigned short* __restrict__ h1_bf)
{
    __shared__ __align__(16) char smem[34816];
    const int bx = blockIdx.x;
    if (bx < B_ * L_) {
        edge_body(smem, bx, token_id, is_periodic, pos, adj, nte,
                  gbf_means, gbf_stds, gbf_mul, gbf_bias, b1, b2, Wpos,
                  W1, W2, pfe_bf, ef_bf, out_pab, padout);
    } else {
        const int tsb = bx - B_ * L_;          // [0,384): 24 m-blocks x 16 n-blocks
        const int m0 = (tsb >> 4) * 32;
        const int n0 = (tsb & 15) * 64;
        ts1_body(smem, m0, n0, time_step, clean, Wt1, bt1, h1_bf);
    }
}

// ---------------------------------------------------------------------------
// Fused ts2 + pe_gemm + combine. grid (16,24), BM=32, BN=64.
// te = h1@Wt2^T + bt2 (K=1024, B f32 staged);
// pe = pfe@Wpfe^T + ef@Wproj^T + bproj (two K=128 phases, B f32 staged);
// outputs: out_te, out_pe (pad rows zeroed), out_x = embed + te + pe.
// ---------------------------------------------------------------------------
__global__ __launch_bounds__(256) void ts2_pe_kernel(
    const unsigned short* __restrict__ h1_bf,
    const float* __restrict__ Wt2,
    const float* __restrict__ bt2,
    const unsigned short* __restrict__ pfe_bf,
    const unsigned short* __restrict__ ef_bf,
    const float* __restrict__ Wpfe,
    const float* __restrict__ Wproj,
    const float* __restrict__ bproj,
    const int* __restrict__ token,
    const float* __restrict__ embed_w,
    float* __restrict__ outTE,
    float* __restrict__ outPE,
    float* __restrict__ outX)
{
    __shared__ __align__(16) char smem[26112];
    const int tid  = threadIdx.x;
    const int lane = tid & 63;
    const int wave = tid >> 6;
    const int l15  = lane & 15;
    const int quad = lane >> 4;
    const int mt   = wave & 1;
    const int np   = wave >> 1;
    const int m0 = blockIdx.y * 32, n0 = blockIdx.x * 64;

    // ---- phase 1: te accumulation (K=1024)
    f32x4 accTE[2];
    gemm_ts_body(smem, m0, n0, h1_bf, Wt2, bt2, nullptr, D_, D_, 0, accTE);

    // ---- phase 2: pe accumulation (two K=128 passes; B converted from f32)
    unsigned short (*sA2)[136] = (unsigned short(*)[136])smem;
    unsigned short (*sB2)[136] = (unsigned short(*)[136])(smem + 8704);
    f32x4 accPE[2];
#pragma unroll
    for (int t = 0; t < 2; ++t) accPE[t] = (f32x4){0.f, 0.f, 0.f, 0.f};

    for (int phase = 0; phase < 2; ++phase) {
        const unsigned short* Ap = phase ? ef_bf : pfe_bf;   // (768,128) bf16
        const float* Bpf = phase ? Wproj : Wpfe;             // (1024,128) f32
#pragma unroll
        for (int e = tid; e < 512; e += 256) {
            const int r = e >> 4, c8 = (e & 15) * 8;
            *(uint4*)&sA2[r][c8] = *(const uint4*)&Ap[(size_t)(m0 + r) * K_ + c8];
        }
#pragma unroll
        for (int e = tid; e < 2048; e += 256) {
            const int r = e >> 5, c4 = (e & 31) * 4;
            const float4 v = *(const float4*)&Bpf[(size_t)(n0 + r) * K_ + c4];
            ushort4 p; p.x = f2bf(v.x); p.y = f2bf(v.y); p.z = f2bf(v.z); p.w = f2bf(v.w);
            *(ushort4*)&sB2[r][c4] = p;
        }
        __syncthreads();
#pragma unroll
        for (int ks = 0; ks < 4; ++ks) {
            const bf16x8 av = *(const bf16x8*)&sA2[mt * 16 + l15][ks * 32 + quad * 8];
#pragma unroll
            for (int t = 0; t < 2; ++t) {
                const bf16x8 bv = *(const bf16x8*)&sB2[(np * 2 + t) * 16 + l15][ks * 32 + quad * 8];
                accPE[t] = __builtin_amdgcn_mfma_f32_16x16x32_bf16(av, bv, accPE[t], 0, 0, 0);
            }
        }
        __syncthreads();
    }

    // ---- epilogue: te, pe, x
#pragma unroll
    for (int t = 0; t < 2; ++t) {
        const int nc = n0 + (np * 2 + t) * 16 + l15;
        const float bte = bt2[nc];
        const float bpe = bproj[nc];
#pragma unroll
        for (int r = 0; r < 4; ++r) {
            const int mr = m0 + mt * 16 + quad * 4 + r;
            const int tok = token[mr];
            const float te = accTE[t][r] + bte;
            const float pe = (tok == 0) ? 0.0f : (accPE[t][r] + bpe);
            outTE[(size_t)mr * D_ + nc] = te;
            outPE[(size_t)mr * D_ + nc] = pe;
            outX[(size_t)mr * D_ + nc] = embed_w[(size_t)tok * D_ + nc] + te + pe;
        }
    }
}

// ---------------------------------------------------------------------------
extern "C" void kernel_launch(void* const* d_in, const int* in_sizes, int n_in,
                              void* d_out, int out_size, void* d_ws, size_t ws_size,
                              hipStream_t stream) {
    const int*           token_id    = (const int*)d_in[0];
    const unsigned char* is_periodic = (const unsigned char*)d_in[1];
    const float*         pos         = (const float*)d_in[2];
    const unsigned char* adj         = (const unsigned char*)d_in[3];
    const int*           nte         = (const int*)d_in[4];
    const float*         time_step   = (const float*)d_in[5];
    const unsigned char* clean_mask  = (const unsigned char*)d_in[6];
    const float*         embed_w     = (const float*)d_in[7];
    const float*         Wpos        = (const float*)d_in[8];
    const float*         Wpfe        = (const float*)d_in[9];
    const float*         gbf_means   = (const float*)d_in[10];
    const float*         gbf_stds    = (const float*)d_in[11];
    const float*         gbf_mul     = (const float*)d_in[12];
    const float*         gbf_bias    = (const float*)d_in[13];
    const float*         W1          = (const float*)d_in[14];
    const float*         b1          = (const float*)d_in[15];
    const float*         W2          = (const float*)d_in[16];
    const float*         b2          = (const float*)d_in[17];
    const float*         Wproj       = (const float*)d_in[18];
    const float*         bproj       = (const float*)d_in[19];
    const float*         Wt1         = (const float*)d_in[20];
    const float*         bt1         = (const float*)d_in[21];
    const float*         Wt2         = (const float*)d_in[22];
    const float*         bt2         = (const float*)d_in[23];

    float* out = (float*)d_out;
    float* out_x   = out;                 // (B,L,D)
    float* out_pad = out + 786432;        // (B,L)
    float* out_te  = out + 787200;        // (B,L,D)
    float* out_pab = out + 1573632;       // (B,H,L,L)
    float* out_pe  = out + 11010816;      // (B,L,D)

    // workspace (ushort units), ~2.0 MB
    unsigned short* wsu = (unsigned short*)d_ws;
    unsigned short* h1_bf  = wsu;                  // 786432
    unsigned short* pfe_bf = wsu + 786432;         // 98304
    unsigned short* ef_bf  = wsu + 884736;         // 98304

    edge_ts1<<<dim3(B_ * L_ + 384), dim3(256), 0, stream>>>(
        token_id, is_periodic, pos, adj, nte, gbf_means, gbf_stds, gbf_mul, gbf_bias,
        b1, b2, Wpos, W1, W2, pfe_bf, ef_bf, out_pab, out_pad,
        time_step, clean_mask, Wt1, bt1, h1_bf);
    ts2_pe_kernel<<<dim3(16, 24), dim3(256), 0, stream>>>(
        h1_bf, Wt2, bt2, pfe_bf, ef_bf, Wpfe, Wproj, bproj, token_id, embed_w,
        out_te, out_pe, out_x);
}

// Round 13
// 184.590 us; speedup vs baseline: 1.1408x; 1.1408x over previous
//
#include <hip/hip_runtime.h>
#include <stddef.h>

#define B_ 2
#define L_ 384
#define D_ 1024
#define K_ 128
#define H_ 32

#define MINV (-3.402823466e38f)
// Exported -inf sentinel: must stay FINITE after bf16 rounding (bf16 max ~3.39e38).
#define NEG_BIG (-1.0e38f)
#define SCALING_ 0.08838834764831845f
#define INV_SQRT_2PI 0.3989422804014327f

typedef __attribute__((ext_vector_type(8))) short bf16x8;
typedef __attribute__((ext_vector_type(4))) float f32x4;

__device__ __forceinline__ float finitize(float x) {
    return fminf(fmaxf(x, -1.0e38f), 1.0e38f);
}
__device__ __forceinline__ unsigned short f2bf(float x) {
    unsigned int u = __float_as_uint(x);
    u += 0x7FFFu + ((u >> 16) & 1u);
    return (unsigned short)(u >> 16);
}
__device__ __forceinline__ unsigned short f2bf_rtz(float x) {
    return (unsigned short)(__float_as_uint(x) >> 16);
}
// tanh-form gelu: max abs err ~3e-4, 1 exp + 1 rcp
__device__ __forceinline__ float gelu_tanh(float x) {
    const float x2 = x * x;
    const float z = x * fmaf(0.0356774081f, x2, 0.7978845608f);
    const float e = __expf(2.0f * z);
    const float t = fmaf(-2.0f, __builtin_amdgcn_rcpf(e + 1.0f), 1.0f);
    const float hx = 0.5f * x;
    return fmaf(hx, t, hx);
}

// ---------------------------------------------------------------------------
// prep+sin fused: blocks [0,1300) convert W1/W2/Wpfe/Wproj/Wt2 f32->bf16
// (332800 float4 chunks); blocks [1300,2068) sinusoidal feats + padding_mask.
// ---------------------------------------------------------------------------
__global__ __launch_bounds__(256) void prep_sin_kernel(
    const float* __restrict__ W1, const float* __restrict__ W2,
    const float* __restrict__ Wpfe, const float* __restrict__ Wproj,
    const float* __restrict__ Wt2,
    unsigned short* __restrict__ W1bf, unsigned short* __restrict__ W2bf,
    unsigned short* __restrict__ Wpfebf, unsigned short* __restrict__ Wprojbf,
    unsigned short* __restrict__ Wt2bf,
    const float* __restrict__ time_step, const unsigned char* __restrict__ clean,
    const int* __restrict__ token, unsigned short* __restrict__ sin_bf,
    float* __restrict__ padout)
{
    const int blk = blockIdx.x;
    if (blk < 1300) {
        const int i = blk * 256 + threadIdx.x;
        const float* src; unsigned short* dst; int off;
        if (i < 4096)       { src = W1;    dst = W1bf;    off = i; }
        else if (i < 5120)  { src = W2;    dst = W2bf;    off = i - 4096; }
        else if (i < 37888) { src = Wpfe;  dst = Wpfebf;  off = i - 5120; }
        else if (i < 70656) { src = Wproj; dst = Wprojbf; off = i - 37888; }
        else                { src = Wt2;   dst = Wt2bf;   off = i - 70656; }
        const float4 v = ((const float4*)src)[off];
        ushort4 p; p.x = f2bf(v.x); p.y = f2bf(v.y); p.z = f2bf(v.z); p.w = f2bf(v.w);
        ((ushort4*)dst)[off] = p;
    } else {
        const int row = blk - 1300;
        if (threadIdx.x == 0) padout[row] = (token[row] == 0) ? 1.0f : 0.0f;
        const float t = (clean[row] ? 0.0f : time_step[row]) * 1000.0f;
        for (int k = threadIdx.x; k < 512; k += 256) {
            const float f = __expf(-9.210340371976184f * (float)k * (1.0f / 512.0f));
            const float ang = t * f;
            sin_bf[(size_t)row * D_ + k]       = f2bf(__sinf(ang));
            sin_bf[(size_t)row * D_ + 512 + k] = f2bf(__cosf(ang));
        }
    }
}

// ---------------------------------------------------------------------------
// time-MLP GEMM body (ts1): A bf16 (M,Kd), B f32 (N,Kd) converted in staging.
// BM=32, BN=64, BK=64, 4 waves, register prefetch. (B f32 is fine here only
// because ts1 runs co-scheduled under edge — its latency is hidden.)
// smem: sA[32][72] us @0 (4608 B), sB[64][72] us @4608 (9216 B) = 13824 B
// ---------------------------------------------------------------------------
__device__ __forceinline__ void gemm_ts_body(
    char* smem, int m0, int n0,
    const unsigned short* __restrict__ A, const float* __restrict__ Bw,
    const float* __restrict__ bias, void* __restrict__ Cv,
    int N, int Kd, int act)
{
    unsigned short (*sA)[72] = (unsigned short(*)[72])smem;
    unsigned short (*sB)[72] = (unsigned short(*)[72])(smem + 4608);
    const int tid  = threadIdx.x;
    const int lane = tid & 63;
    const int wave = tid >> 6;
    const int l15  = lane & 15;
    const int quad = lane >> 4;
    const int mt   = wave & 1;
    const int np   = wave >> 1;

    const int ar = tid >> 3, ac = (tid & 7) * 8;
    const int bc4 = (tid & 15) * 4;

    f32x4 acc[2];
#pragma unroll
    for (int t = 0; t < 2; ++t) acc[t] = (f32x4){0.f, 0.f, 0.f, 0.f};

    uint4 ra = *(const uint4*)&A[(size_t)(m0 + ar) * Kd + ac];
    float4 rbv[4];
#pragma unroll
    for (int c = 0; c < 4; ++c)
        rbv[c] = *(const float4*)&Bw[(size_t)(n0 + ((tid + c * 256) >> 4)) * Kd + bc4];

    for (int k0 = 0; k0 < Kd; k0 += 64) {
        *(uint4*)&sA[ar][ac] = ra;
#pragma unroll
        for (int c = 0; c < 4; ++c) {
            ushort4 p;
            p.x = f2bf(rbv[c].x); p.y = f2bf(rbv[c].y);
            p.z = f2bf(rbv[c].z); p.w = f2bf(rbv[c].w);
            *(ushort4*)&sB[(tid + c * 256) >> 4][bc4] = p;
        }
        __syncthreads();
        if (k0 + 64 < Kd) {
            ra = *(const uint4*)&A[(size_t)(m0 + ar) * Kd + k0 + 64 + ac];
#pragma unroll
            for (int c = 0; c < 4; ++c)
                rbv[c] = *(const float4*)&Bw[(size_t)(n0 + ((tid + c * 256) >> 4)) * Kd + k0 + 64 + bc4];
        }
#pragma unroll
        for (int kk = 0; kk < 64; kk += 32) {
            const bf16x8 av = *(const bf16x8*)&sA[mt * 16 + l15][kk + quad * 8];
#pragma unroll
            for (int t = 0; t < 2; ++t) {
                const bf16x8 bv = *(const bf16x8*)&sB[(np * 2 + t) * 16 + l15][kk + quad * 8];
                acc[t] = __builtin_amdgcn_mfma_f32_16x16x32_bf16(av, bv, acc[t], 0, 0, 0);
            }
        }
        __syncthreads();
    }
#pragma unroll
    for (int t = 0; t < 2; ++t) {
        const int nc = n0 + (np * 2 + t) * 16 + l15;
        const float bv = bias[nc];
#pragma unroll
        for (int r = 0; r < 4; ++r) {
            const int mr = m0 + mt * 16 + quad * 4 + r;
            float v = acc[t][r] + bv;
            if (act) {
                v = v / (1.0f + __expf(-v));
                ((unsigned short*)Cv)[(size_t)mr * N + nc] = f2bf(v);
            } else {
                ((float*)Cv)[(size_t)mr * N + nc] = v;
            }
        }
    }
}

// ---------------------------------------------------------------------------
// Edge body (R8 structure, known-good; W1bf/W2bf from prep).
// smem pool (34816 B): sEF@0 [2][32][136]us, sACT@17408 [32][136]us,
// sGab@26112 [32][33]f, sD@30336 [384]f, sRed@31872 [256]f,
// sYall@32896 [384]f, sPadCol@34432 [384]uc
// ---------------------------------------------------------------------------
__device__ __forceinline__ void edge_body(
    char* smem, int row,
    const int* __restrict__ token_id,
    const unsigned char* __restrict__ is_periodic,
    const float* __restrict__ pos,
    const unsigned char* __restrict__ adj,
    const int* __restrict__ nte,
    const float* __restrict__ gbf_means,
    const float* __restrict__ gbf_stds,
    const float* __restrict__ gbf_mul,
    const float* __restrict__ gbf_bias,
    const float* __restrict__ b1,
    const float* __restrict__ b2,
    const float* __restrict__ Wpos,
    const unsigned short* __restrict__ W1bf,
    const unsigned short* __restrict__ W2bf,
    unsigned short* __restrict__ pfe_bf,
    unsigned short* __restrict__ ef_bf,
    float* __restrict__ out_pab)
{
    const int b = row / L_;
    const int i = row - b * L_;
    const int tid = threadIdx.x;

    const int tok_i = token_id[row];
    if (tok_i == 0) {
        for (int idx = tid; idx < H_ * L_; idx += 256) {
            const int h = idx / L_;
            const int j = idx - h * L_;
            out_pab[((size_t)(b * H_ + h) * L_ + i) * L_ + j] = 0.0f;
        }
        if (tid < K_) {
            pfe_bf[(size_t)row * K_ + tid] = 0;
            ef_bf[(size_t)row * K_ + tid]  = 0;
        }
        return;
    }

    typedef unsigned short efbuf_t[32][136];
    efbuf_t* sEF = (efbuf_t*)smem;
    unsigned short (*sACT)[136] = (unsigned short(*)[136])(smem + 17408);
    float (*sGab)[33] = (float(*)[33])(smem + 26112);
    float* sD      = (float*)(smem + 30336);
    float* sRed    = (float*)(smem + 31872);
    float* sYall   = (float*)(smem + 32896);
    unsigned char* sPadCol = (unsigned char*)(smem + 34432);

    for (int j = tid; j < L_; j += 256)
        sPadCol[j] = (token_id[b * L_ + j] == 0) ? 1 : 0;

    const float px = pos[(size_t)row * 3 + 0];
    const float py = pos[(size_t)row * 3 + 1];
    const float pz = pos[(size_t)row * 3 + 2];
    for (int jg2 = tid; jg2 < L_; jg2 += 256) {
        const float dx = px - pos[(size_t)(b * L_ + jg2) * 3 + 0];
        const float dy = py - pos[(size_t)(b * L_ + jg2) * 3 + 1];
        const float dz = pz - pos[(size_t)(b * L_ + jg2) * 3 + 2];
        const float dist = sqrtf(fmaxf(dx * dx + dy * dy + dz * dz, 1e-12f));
        const size_t eoff = ((size_t)(b * L_ + i) * L_ + jg2) * 2;
        const int e0 = nte[eoff], e1 = nte[eoff + 1];
        sYall[jg2] = (gbf_mul[e0] + gbf_mul[e1]) * dist + (gbf_bias[e0] + gbf_bias[e1]);
    }

    const int lane = tid & 63;
    const int wave = tid >> 6;
    const int l15  = lane & 15;
    const int quad = lane >> 4;
    const int mt   = wave & 1;
    const int ntb  = (wave >> 1) * 4;
    float rb1[4];
#pragma unroll
    for (int nt = 0; nt < 4; ++nt) rb1[nt] = b1[(ntb + nt) * 16 + l15];
    const int hc = (wave >> 1) * 16 + l15;
    const float rb2 = b2[hc];
    bf16x8 w1f[4][4];
#pragma unroll
    for (int ks = 0; ks < 4; ++ks)
#pragma unroll
        for (int nt = 0; nt < 4; ++nt)
            w1f[ks][nt] = *(const bf16x8*)&W1bf[((ntb + nt) * 16 + l15) * K_ + ks * 32 + quad * 8];
    bf16x8 bv2[4];
#pragma unroll
    for (int ks = 0; ks < 4; ++ks)
        bv2[ks] = *(const bf16x8*)&W2bf[hc * K_ + ks * 32 + quad * 8];

    const int kg4 = (tid & 31) * 4;
    const int jg  = tid >> 5;
    const int jb  = jg * 4;
    float meanv[4], istdv[4], cKv[4];
#pragma unroll
    for (int c = 0; c < 4; ++c) {
        meanv[c] = gbf_means[kg4 + c];
        const float s = fabsf(gbf_stds[kg4 + c]) + 1e-5f;
        istdv[c] = 1.0f / s;
        cKv[c]   = INV_SQRT_2PI * istdv[c];
    }
    float efs[4] = {0.f, 0.f, 0.f, 0.f};

    __syncthreads();

#pragma unroll
    for (int jj = 0; jj < 4; ++jj) {
        const int j = jb + jj;
        const float y = sYall[j];
        const bool ok = !sPadCol[j];
        ushort4 p;
#pragma unroll
        for (int c = 0; c < 4; ++c) {
            const float a = (y - meanv[c]) * istdv[c];
            const float ef = __expf(-0.5f * a * a) * cKv[c];
            ((unsigned short*)&p)[c] = f2bf_rtz(ef);
            if (ok) efs[c] += ef;
        }
        *(ushort4*)&sEF[0][j][kg4] = p;
    }
    __syncthreads();

    for (int tile = 0; tile < L_ / 32; ++tile) {
        const int jt0 = tile * 32;
        const int cur = tile & 1, nxt = cur ^ 1;

        f32x4 acc1[4];
#pragma unroll
        for (int nt = 0; nt < 4; ++nt) acc1[nt] = (f32x4){0.f, 0.f, 0.f, 0.f};
#pragma unroll
        for (int ks = 0; ks < 4; ++ks) {
            const bf16x8 av = *(const bf16x8*)&sEF[cur][mt * 16 + l15][ks * 32 + quad * 8];
#pragma unroll
            for (int nt = 0; nt < 4; ++nt)
                acc1[nt] = __builtin_amdgcn_mfma_f32_16x16x32_bf16(av, w1f[ks][nt], acc1[nt], 0, 0, 0);
        }

        if (tile + 1 < L_ / 32) {
            const int jn0 = jt0 + 32;
#pragma unroll
            for (int jj = 0; jj < 4; ++jj) {
                const int j = jb + jj;
                const float y = sYall[jn0 + j];
                const bool ok = !sPadCol[jn0 + j];
                ushort4 p;
#pragma unroll
                for (int c = 0; c < 4; ++c) {
                    const float a = (y - meanv[c]) * istdv[c];
                    const float ef = __expf(-0.5f * a * a) * cKv[c];
                    ((unsigned short*)&p)[c] = f2bf_rtz(ef);
                    if (ok) efs[c] += ef;
                }
                *(ushort4*)&sEF[nxt][j][kg4] = p;
            }
        }

#pragma unroll
        for (int nt = 0; nt < 4; ++nt) {
            const int kkc = (ntb + nt) * 16 + l15;
#pragma unroll
            for (int r = 0; r < 4; ++r) {
                const float v = gelu_tanh(acc1[nt][r] + rb1[nt]);
                sACT[mt * 16 + quad * 4 + r][kkc] = f2bf_rtz(v);
            }
        }
        __syncthreads();   // A

        f32x4 acc2 = (f32x4){0.f, 0.f, 0.f, 0.f};
#pragma unroll
        for (int ks = 0; ks < 4; ++ks) {
            const bf16x8 av = *(const bf16x8*)&sACT[mt * 16 + l15][ks * 32 + quad * 8];
            acc2 = __builtin_amdgcn_mfma_f32_16x16x32_bf16(av, bv2[ks], acc2, 0, 0, 0);
        }
        const int jl0 = mt * 16 + quad * 4;
#pragma unroll
        for (int r = 0; r < 4; ++r) sGab[jl0 + r][hc] = acc2[r] + rb2;
        __syncthreads();   // B

        {
            const int h = tid >> 3, f = tid & 7;
            const int jb2 = f * 4;
            float4 st;
#pragma unroll
            for (int r = 0; r < 4; ++r) {
                float v = finitize(sGab[jb2 + r][h]);
                if (sPadCol[jt0 + jb2 + r]) v = NEG_BIG;
                ((float*)&st)[r] = v;
            }
            *(float4*)&out_pab[((size_t)(b * H_ + h) * L_ + i) * L_ + jt0 + jb2] = st;
        }
        if (tid < 32) {
            float s = 0.0f;
#pragma unroll
            for (int h = 0; h < 32; ++h) s += sGab[tid][h];
            sD[jt0 + tid] = s;
        }
    }

    {
        float* efScr = (float*)sACT;
#pragma unroll
        for (int c = 0; c < 4; ++c) efScr[jg * 128 + kg4 + c] = efs[c];
    }
    __syncthreads();
    if (tid < 128) {
        const float* efScr = (const float*)sACT;
        float s = 0.0f;
#pragma unroll
        for (int g = 0; g < 8; ++g) s += efScr[g * 128 + tid];
        ef_bf[(size_t)row * K_ + tid] = f2bf(s);
    }
    __syncthreads();

    const bool molecule = (tok_i <= 129) && (is_periodic[b] == 0);
    float lmax = -INFINITY;
    for (int j = tid; j < L_; j += 256) {
        const bool colpad = sPadCol[j] != 0;
        const bool adj_eff = (adj[((size_t)(b * L_ + i)) * L_ + j] != 0) || (!molecule);
        const float dv = (colpad || !adj_eff) ? MINV : sD[j];
        const float s = dv * SCALING_;
        sD[j] = s;
        lmax = fmaxf(lmax, s);
    }
#pragma unroll
    for (int off = 32; off > 0; off >>= 1) lmax = fmaxf(lmax, __shfl_xor(lmax, off));
    if (lane == 0) sRed[wave] = lmax;
    __syncthreads();
    const float smax = fmaxf(fmaxf(sRed[0], sRed[1]), fmaxf(sRed[2], sRed[3]));
    float lsum = 0.0f;
    for (int j = tid; j < L_; j += 256) {
        const float e = __expf(sD[j] - smax);
        sD[j] = e;
        lsum += e;
    }
#pragma unroll
    for (int off = 32; off > 0; off >>= 1) lsum += __shfl_xor(lsum, off);
    if (lane == 0) sRed[4 + wave] = lsum;
    __syncthreads();
    const float inv = 1.0f / (sRed[4] + sRed[5] + sRed[6] + sRed[7]);

    float a0 = 0.f, a1 = 0.f, a2 = 0.f;
    for (int j = tid; j < L_; j += 256) {
        if (!sPadCol[j]) {
            const float e = sD[j];
            a0 += e * pos[(size_t)(b * L_ + j) * 3 + 0];
            a1 += e * pos[(size_t)(b * L_ + j) * 3 + 1];
            a2 += e * pos[(size_t)(b * L_ + j) * 3 + 2];
        }
    }
#pragma unroll
    for (int off = 32; off > 0; off >>= 1) {
        a0 += __shfl_xor(a0, off);
        a1 += __shfl_xor(a1, off);
        a2 += __shfl_xor(a2, off);
    }
    if (lane == 0) { sRed[8 + wave] = a0; sRed[12 + wave] = a1; sRed[16 + wave] = a2; }
    __syncthreads();
    if (tid < 128) {
        const float m0 = sRed[8] + sRed[9] + sRed[10] + sRed[11];
        const float m1 = sRed[12] + sRed[13] + sRed[14] + sRed[15];
        const float m2 = sRed[16] + sRed[17] + sRed[18] + sRed[19];
        const float w0 = Wpos[tid * 3 + 0], w1 = Wpos[tid * 3 + 1], w2 = Wpos[tid * 3 + 2];
        pfe_bf[(size_t)row * K_ + tid] = f2bf((m0 * w0 + m1 * w1 + m2 * w2) * inv);
    }
}

// ---------------------------------------------------------------------------
// Fat kernel: blocks [0,768) = edge rows; [768,1152) = time-MLP layer 1.
// ---------------------------------------------------------------------------
__global__ __launch_bounds__(256, 3) void edge_ts1(
    const int* __restrict__ token_id,
    const unsigned char* __restrict__ is_periodic,
    const float* __restrict__ pos,
    const unsigned char* __restrict__ adj,
    const int* __restrict__ nte,
    const float* __restrict__ gbf_means,
    const float* __restrict__ gbf_stds,
    const float* __restrict__ gbf_mul,
    const float* __restrict__ gbf_bias,
    const float* __restrict__ b1,
    const float* __restrict__ b2,
    const float* __restrict__ Wpos,
    const unsigned short* __restrict__ W1bf,
    const unsigned short* __restrict__ W2bf,
    unsigned short* __restrict__ pfe_bf,
    unsigned short* __restrict__ ef_bf,
    float* __restrict__ out_pab,
    const unsigned short* __restrict__ sin_bf,
    const float* __restrict__ Wt1,
    const float* __restrict__ bt1,
    unsigned short* __restrict__ h1_bf)
{
    __shared__ __align__(16) char smem[34816];
    const int bx = blockIdx.x;
    if (bx < B_ * L_) {
        edge_body(smem, bx, token_id, is_periodic, pos, adj, nte,
                  gbf_means, gbf_stds, gbf_mul, gbf_bias, b1, b2, Wpos,
                  W1bf, W2bf, pfe_bf, ef_bf, out_pab);
    } else {
        const int tsb = bx - B_ * L_;          // [0,384): 24 m-blocks x 16 n-blocks
        const int m0 = (tsb >> 4) * 32;
        const int n0 = (tsb & 15) * 64;
        gemm_ts_body(smem, m0, n0, sin_bf, Wt1, bt1, (void*)h1_bf, D_, D_, 1);
    }
}

// ---------------------------------------------------------------------------
// Fused ts2 + pe_gemm + combine. grid (16,24), BM=32, BN=64.
// Phase 1: te = h1@Wt2^T + bt2, K=1024, ALL-bf16 (Wt2bf from prep);
// Phase 2: pe = pfe@Wpfe^T + ef@Wproj^T + bproj, two K=128 bf16 passes;
// Epilogue: out_te, out_pe (pad rows zeroed), out_x = embed + te + pe.
// smem pool: phase1 13824 B; phase2 sA[32][136]@0 + sB[64][136]@8704 = 26112 B.
// ---------------------------------------------------------------------------
__global__ __launch_bounds__(256) void ts2_pe_kernel(
    const unsigned short* __restrict__ h1_bf,
    const unsigned short* __restrict__ Wt2bf,
    const float* __restrict__ bt2,
    const unsigned short* __restrict__ pfe_bf,
    const unsigned short* __restrict__ ef_bf,
    const unsigned short* __restrict__ Wpfebf,
    const unsigned short* __restrict__ Wprojbf,
    const float* __restrict__ bproj,
    const int* __restrict__ token,
    const float* __restrict__ embed_w,
    float* __restrict__ outTE,
    float* __restrict__ outPE,
    float* __restrict__ outX)
{
    __shared__ __align__(16) char smem[26112];
    const int tid  = threadIdx.x;
    const int lane = tid & 63;
    const int wave = tid >> 6;
    const int l15  = lane & 15;
    const int quad = lane >> 4;
    const int mt   = wave & 1;
    const int np   = wave >> 1;
    const int m0 = blockIdx.y * 32, n0 = blockIdx.x * 64;

    // ---- phase 1: te accumulation (K=1024, all-bf16, register prefetch)
    f32x4 accTE[2];
#pragma unroll
    for (int t = 0; t < 2; ++t) accTE[t] = (f32x4){0.f, 0.f, 0.f, 0.f};
    {
        unsigned short (*sA)[72] = (unsigned short(*)[72])smem;
        unsigned short (*sB)[72] = (unsigned short(*)[72])(smem + 4608);
        const int ar = tid >> 3, ac = (tid & 7) * 8;
        const int br1r = (tid + 256) >> 3;   // rows 32..63

        uint4 ra  = *(const uint4*)&h1_bf[(size_t)(m0 + ar) * D_ + ac];
        uint4 rb0 = *(const uint4*)&Wt2bf[(size_t)(n0 + ar) * D_ + ac];
        uint4 rb1 = *(const uint4*)&Wt2bf[(size_t)(n0 + br1r) * D_ + ac];

        for (int k0 = 0; k0 < D_; k0 += 64) {
            *(uint4*)&sA[ar][ac]   = ra;
            *(uint4*)&sB[ar][ac]   = rb0;
            *(uint4*)&sB[br1r][ac] = rb1;
            __syncthreads();
            if (k0 + 64 < D_) {
                ra  = *(const uint4*)&h1_bf[(size_t)(m0 + ar) * D_ + k0 + 64 + ac];
                rb0 = *(const uint4*)&Wt2bf[(size_t)(n0 + ar) * D_ + k0 + 64 + ac];
                rb1 = *(const uint4*)&Wt2bf[(size_t)(n0 + br1r) * D_ + k0 + 64 + ac];
            }
#pragma unroll
            for (int kk = 0; kk < 64; kk += 32) {
                const bf16x8 av = *(const bf16x8*)&sA[mt * 16 + l15][kk + quad * 8];
#pragma unroll
                for (int t = 0; t < 2; ++t) {
                    const bf16x8 bv = *(const bf16x8*)&sB[(np * 2 + t) * 16 + l15][kk + quad * 8];
                    accTE[t] = __builtin_amdgcn_mfma_f32_16x16x32_bf16(av, bv, accTE[t], 0, 0, 0);
                }
            }
            __syncthreads();
        }
    }

    // ---- phase 2: pe accumulation (two K=128 passes, all-bf16)
    unsigned short (*sA2)[136] = (unsigned short(*)[136])smem;
    unsigned short (*sB2)[136] = (unsigned short(*)[136])(smem + 8704);
    f32x4 accPE[2];
#pragma unroll
    for (int t = 0; t < 2; ++t) accPE[t] = (f32x4){0.f, 0.f, 0.f, 0.f};

    for (int phase = 0; phase < 2; ++phase) {
        const unsigned short* Ap = phase ? ef_bf : pfe_bf;       // (768,128)
        const unsigned short* Bp = phase ? Wprojbf : Wpfebf;     // (1024,128)
#pragma unroll
        for (int e = tid; e < 512; e += 256) {
            const int r = e >> 4, c8 = (e & 15) * 8;
            *(uint4*)&sA2[r][c8] = *(const uint4*)&Ap[(size_t)(m0 + r) * K_ + c8];
        }
#pragma unroll
        for (int e = tid; e < 1024; e += 256) {
            const int r = e >> 4, c8 = (e & 15) * 8;
            *(uint4*)&sB2[r][c8] = *(const uint4*)&Bp[(size_t)(n0 + r) * K_ + c8];
        }
        __syncthreads();
#pragma unroll
        for (int ks = 0; ks < 4; ++ks) {
            const bf16x8 av = *(const bf16x8*)&sA2[mt * 16 + l15][ks * 32 + quad * 8];
#pragma unroll
            for (int t = 0; t < 2; ++t) {
                const bf16x8 bv = *(const bf16x8*)&sB2[(np * 2 + t) * 16 + l15][ks * 32 + quad * 8];
                accPE[t] = __builtin_amdgcn_mfma_f32_16x16x32_bf16(av, bv, accPE[t], 0, 0, 0);
            }
        }
        __syncthreads();
    }

    // ---- epilogue: te, pe, x
#pragma unroll
    for (int t = 0; t < 2; ++t) {
        const int nc = n0 + (np * 2 + t) * 16 + l15;
        const float bte = bt2[nc];
        const float bpe = bproj[nc];
#pragma unroll
        for (int r = 0; r < 4; ++r) {
            const int mr = m0 + mt * 16 + quad * 4 + r;
            const int tok = token[mr];
            const float te = accTE[t][r] + bte;
            const float pe = (tok == 0) ? 0.0f : (accPE[t][r] + bpe);
            outTE[(size_t)mr * D_ + nc] = te;
            outPE[(size_t)mr * D_ + nc] = pe;
            outX[(size_t)mr * D_ + nc] = embed_w[(size_t)tok * D_ + nc] + te + pe;
        }
    }
}

// ---------------------------------------------------------------------------
extern "C" void kernel_launch(void* const* d_in, const int* in_sizes, int n_in,
                              void* d_out, int out_size, void* d_ws, size_t ws_size,
                              hipStream_t stream) {
    const int*           token_id    = (const int*)d_in[0];
    const unsigned char* is_periodic = (const unsigned char*)d_in[1];
    const float*         pos         = (const float*)d_in[2];
    const unsigned char* adj         = (const unsigned char*)d_in[3];
    const int*           nte         = (const int*)d_in[4];
    const float*         time_step   = (const float*)d_in[5];
    const unsigned char* clean_mask  = (const unsigned char*)d_in[6];
    const float*         embed_w     = (const float*)d_in[7];
    const float*         Wpos        = (const float*)d_in[8];
    const float*         Wpfe        = (const float*)d_in[9];
    const float*         gbf_means   = (const float*)d_in[10];
    const float*         gbf_stds    = (const float*)d_in[11];
    const float*         gbf_mul     = (const float*)d_in[12];
    const float*         gbf_bias    = (const float*)d_in[13];
    const float*         W1          = (const float*)d_in[14];
    const float*         b1          = (const float*)d_in[15];
    const float*         W2          = (const float*)d_in[16];
    const float*         b2          = (const float*)d_in[17];
    const float*         Wproj       = (const float*)d_in[18];
    const float*         bproj       = (const float*)d_in[19];
    const float*         Wt1         = (const float*)d_in[20];
    const float*         bt1         = (const float*)d_in[21];
    const float*         Wt2         = (const float*)d_in[22];
    const float*         bt2         = (const float*)d_in[23];

    float* out = (float*)d_out;
    float* out_x   = out;                 // (B,L,D)
    float* out_pad = out + 786432;        // (B,L)
    float* out_te  = out + 787200;        // (B,L,D)
    float* out_pab = out + 1573632;       // (B,H,L,L)
    float* out_pe  = out + 11010816;      // (B,L,D)

    // workspace (ushort units), ~6.2 MB
    unsigned short* wsu = (unsigned short*)d_ws;
    unsigned short* W1bf    = wsu;                 // 16384
    unsigned short* W2bf    = wsu + 16384;         // 4096
    unsigned short* Wpfebf  = wsu + 20480;         // 131072
    unsigned short* Wprojbf = wsu + 151552;        // 131072
    unsigned short* Wt2bf   = wsu + 282624;        // 1048576
    unsigned short* sin_bf  = wsu + 1331200;       // 786432
    unsigned short* h1_bf   = wsu + 2117632;       // 786432
    unsigned short* pfe_bf  = wsu + 2904064;       // 98304
    unsigned short* ef_bf   = wsu + 3002368;       // 98304

    prep_sin_kernel<<<dim3(2068), dim3(256), 0, stream>>>(
        W1, W2, Wpfe, Wproj, Wt2, W1bf, W2bf, Wpfebf, Wprojbf, Wt2bf,
        time_step, clean_mask, token_id, sin_bf, out_pad);
    edge_ts1<<<dim3(B_ * L_ + 384), dim3(256), 0, stream>>>(
        token_id, is_periodic, pos, adj, nte, gbf_means, gbf_stds, gbf_mul, gbf_bias,
        b1, b2, Wpos, W1bf, W2bf, pfe_bf, ef_bf, out_pab,
        sin_bf, Wt1, bt1, h1_bf);
    ts2_pe_kernel<<<dim3(16, 24), dim3(256), 0, stream>>>(
        h1_bf, Wt2bf, bt2, pfe_bf, ef_bf, Wpfebf, Wprojbf, bproj, token_id, embed_w,
        out_te, out_pe, out_x);
}